// Round 16
// baseline (33.759 us; speedup 1.0000x reference)
//
#include <hip/hip_runtime.h>
#include <climits>
#include <float.h>

#define H_     512
#define W_     512
#define C_     80
#define HW_    (H_ * W_)           // 262144
#define NTOT   (C_ * HW_)          // 20,971,520
#define NCHUNK (NTOT / 4)          // 5,242,880 float4 chunks
#define K_     10
#define NB2    2048                // scan blocks
#define NTH    (NB2 * 256)         // 524288 threads -> exactly 10 chunks each
#define BSLOTS 8                   // per-block candidate slots (64 B)
#define TAU    0.999994f           // ~126 expected candidates of 21M uniforms

__device__ __forceinline__ float max3f(float a, float b, float c) {
    return fmaxf(fmaxf(a, b), c);
}

// Fully-unrolled bubble insert into descending (tv, ti); tie -> lower index.
__device__ __forceinline__ void insert10(float (&tv)[K_], int (&ti)[K_],
                                         float s, int ridx) {
#pragma unroll
    for (int j = 0; j < K_; ++j) {
        const bool better = (s > tv[j]) || (s == tv[j] && ridx < ti[j]);
        const float ov = tv[j]; const int oi = ti[j];
        if (better) { tv[j] = s; ti[j] = ridx; s = ov; ridx = oi; }
    }
}

// Merge 256 sorted 10-lists in LDS down to one (result in sv[0]/si[0]).
__device__ __forceinline__ void block_merge(float (*sv)[K_], int (*si)[K_], int t) {
    for (int stride = 128; stride > 0; stride >>= 1) {
        if (t < stride) {
            float mv[K_]; int mi[K_];
            int a = 0, b = 0;
#pragma unroll
            for (int k = 0; k < K_; ++k) {
                const float va = sv[t][a], vb = sv[t + stride][b];
                const int   ia = si[t][a], ib = si[t + stride][b];
                const bool takeA = (va > vb) || (va == vb && ia <= ib);
                if (takeA) { mv[k] = va; mi[k] = ia; ++a; }
                else       { mv[k] = vb; mi[k] = ib; ++b; }
            }
#pragma unroll
            for (int k = 0; k < K_; ++k) { sv[t][k] = mv[k]; si[t][k] = mi[k]; }
        }
        __syncthreads();
    }
}

// ---------------------------------------------------------------------------
// k_scan: r5-style CHUNK scan (the structure whose ~7 us was directly
// accounted in r5), not the r6+ strip scan (ledger says ~28 us). Fixed
// 10-trip unrolled grid walk -> 10 independent float4 loads in flight;
// prefilter = 3 fmax + 4 cmps; full 3x3 window only in the ~0.15% branch.
// Output: r15's LDS compaction -> unconditional per-block count + <=8 slots.
// No global atomics, no pre-zeroed state (poison-proof).
// ---------------------------------------------------------------------------
__global__ __launch_bounds__(256) void k_scan(const float* __restrict__ kp,
                                              int*  __restrict__ gbcnt,
                                              int2* __restrict__ gbpair)
{
    __shared__ int  bcnt_s;
    __shared__ int2 bslots[BSLOTS];
    const int t = threadIdx.x;
    if (t == 0) bcnt_s = 0;
    __syncthreads();

    const int tid = blockIdx.x * 256 + t;

#pragma unroll
    for (int it = 0; it < NCHUNK / NTH; ++it) {       // exactly 10
        const int ch  = tid + it * NTH;
        const int spc = ch & 0xFFFF;                  // chunk within plane
        const float4 b4 = *(const float4*)(kp + ((size_t)ch << 2));

        // prefilter: a kept score equals its raw value, so raw > TAU necessary
        if (__builtin_expect((b4.x > TAU) | (b4.y > TAU) |
                             (b4.z > TAU) | (b4.w > TAU), 0)) {
            const int cls = ch >> 16;                 // 65536 chunks per plane
            const int y   = spc >> 7;
            const int x   = (spc & 127) << 2;
            const float* plane = kp + (cls << 18);

            const int ym1 = (y > 0)      ? y - 1 : 0;
            const int yp1 = (y < H_ - 1) ? y + 1 : H_ - 1;
            const float4 ru = *(const float4*)(plane + (ym1 << 9) + x);
            const float4 rd = *(const float4*)(plane + (yp1 << 9) + x);
            const int xl = (x > 0)      ? x - 1 : 0;
            const int xr = (x + 4 < W_) ? x + 4 : W_ - 1;
            const float la = plane[(ym1 << 9) + xl];
            const float lb = plane[(y   << 9) + xl];
            const float lc = plane[(yp1 << 9) + xl];
            const float ka = plane[(ym1 << 9) + xr];
            const float kb = plane[(y   << 9) + xr];
            const float kc = plane[(yp1 << 9) + xr];

            const float vm0 = max3f(ru.x, b4.x, rd.x);
            const float vm1 = max3f(ru.y, b4.y, rd.y);
            const float vm2 = max3f(ru.z, b4.z, rd.z);
            const float vm3 = max3f(ru.w, b4.w, rd.w);
            const float lv  = (x > 0)      ? max3f(la, lb, lc) : -FLT_MAX;
            const float rv  = (x + 4 < W_) ? max3f(ka, kb, kc) : -FLT_MAX;

            const float w0 = fmaxf(lv, fmaxf(vm0, vm1));
            const float w1 = max3f(vm0, vm1, vm2);
            const float w2 = max3f(vm1, vm2, vm3);
            const float w3 = fmaxf(fmaxf(vm2, vm3), rv);

            const int base = ((y << 9) + x) * C_ + cls;   // reference flat index

            const float vals[4] = { b4.x, b4.y, b4.z, b4.w };
            const float wins[4] = { w0, w1, w2, w3 };
#pragma unroll
            for (int c2 = 0; c2 < 4; ++c2) {
                const float v = vals[c2];
                if (v > TAU && v == wins[c2]) {
                    const int pos = atomicAdd(&bcnt_s, 1);   // LDS atomic
                    if (pos < BSLOTS)
                        bslots[pos] = make_int2(__float_as_int(v),
                                                base + c2 * C_);
                }
            }
        }
    }

    __syncthreads();
    const int c = bcnt_s;
    if (t == 0) gbcnt[blockIdx.x] = c;                // unconditional, every call
    if (t < ((c < BSLOTS) ? c : BSLOTS))
        gbpair[blockIdx.x * BSLOTS + t] = bslots[t];
}

// ---------------------------------------------------------------------------
// k_reduce: one block. Phase 1: coalesced read of 2048 counts (64 lines, one
// round trip) -> LDS worklist of nonzero blocks (~30). Phase 2: those lanes
// gather one 64 B slot line each, fully parallel. Valid iff every c <= 8 and
// total >= 10 (candidates provably contain the global top-10: every candidate
// > TAU >= every non-candidate masked score). Else exhaustive fallback.
// Then decode boxes.
// ---------------------------------------------------------------------------
__global__ __launch_bounds__(256) void k_reduce(const int*  __restrict__ gbcnt,
                                                const int4* __restrict__ gbpair4,
                                                const float* __restrict__ kp,
                                                const float* __restrict__ off,
                                                const float* __restrict__ sz,
                                                float* __restrict__ out)
{
    __shared__ float sv[256][K_];
    __shared__ int   si[256][K_];
    __shared__ int   sn[256], sk[256];
    __shared__ int   wl[NB2];
    __shared__ int   wln;

    const int t = threadIdx.x;
    if (t == 0) wln = 0;
    __syncthreads();

    float tv[K_];
    int   ti[K_];
#pragma unroll
    for (int k = 0; k < K_; ++k) { tv[k] = 0.0f; ti[k] = INT_MAX; }

    // ---- phase 1: counts (coalesced) + worklist ----------------------------
    int myn = 0, myok = 1;
#pragma unroll
    for (int k = 0; k < NB2 / 256; ++k) {      // 8
        const int b = t + k * 256;
        const int c = gbcnt[b];
        if (c < 0 || c > BSLOTS) { myok = 0; }
        else {
            myn += c;
            if (c > 0) {
                const int pos = atomicAdd(&wln, 1);      // LDS atomic
                wl[pos] = b | (c << 16);
            }
        }
    }

    sn[t] = myn; sk[t] = myok;
    __syncthreads();
    for (int st = 128; st > 0; st >>= 1) {
        if (t < st) { sn[t] += sn[t + st]; sk[t] &= sk[t + st]; }
        __syncthreads();
    }
    const bool valid = (sk[0] != 0) && (sn[0] >= K_);
    const int  m     = wln;
    __syncthreads();

    if (valid) {
        // ---- phase 2: parallel gather, one slot-line per lane -------------
        for (int wli = t; wli < m; wli += 256) {
            const int e  = wl[wli];
            const int b  = e & 0xFFFF;
            const int c  = e >> 16;
            const int4 q0 = gbpair4[b * 4 + 0];
            const int4 q1 = gbpair4[b * 4 + 1];
            const int4 q2 = gbpair4[b * 4 + 2];
            const int4 q3 = gbpair4[b * 4 + 3];
            if (c > 0) insert10(tv, ti, __int_as_float(q0.x), q0.y);
            if (c > 1) insert10(tv, ti, __int_as_float(q0.z), q0.w);
            if (c > 2) insert10(tv, ti, __int_as_float(q1.x), q1.y);
            if (c > 3) insert10(tv, ti, __int_as_float(q1.z), q1.w);
            if (c > 4) insert10(tv, ti, __int_as_float(q2.x), q2.y);
            if (c > 5) insert10(tv, ti, __int_as_float(q2.z), q2.w);
            if (c > 6) insert10(tv, ti, __int_as_float(q3.x), q3.y);
            if (c > 7) insert10(tv, ti, __int_as_float(q3.z), q3.w);
        }
    } else {
        // exhaustive fallback (never taken for the benchmark input)
        float thresh = 0.0f;
        for (int idx = t; idx < NTOT; idx += 256) {
            const int cls = idx >> 18;
            const int sp  = idx & (HW_ - 1);
            const int y   = sp >> 9;
            const int x   = sp & (W_ - 1);
            const float* plane = kp + (cls << 18);
            const float v = plane[sp];
            float wmax = v;
            const int yA = (y > 0)      ? y - 1 : 0;
            const int yB = (y < H_ - 1) ? y + 1 : H_ - 1;
            const int xA = (x > 0)      ? x - 1 : 0;
            const int xB = (x < W_ - 1) ? x + 1 : W_ - 1;
            for (int yy = yA; yy <= yB; ++yy)
                for (int xx = xA; xx <= xB; ++xx)
                    wmax = fmaxf(wmax, plane[(yy << 9) + xx]);
            if (v == wmax && v > thresh) {
                insert10(tv, ti, v, sp * C_ + cls);
                thresh = tv[K_ - 1];
            }
        }
    }

#pragma unroll
    for (int k = 0; k < K_; ++k) { sv[t][k] = tv[k]; si[t][k] = ti[k]; }
    __syncthreads();
    block_merge(sv, si, t);

    if (t < K_) {
        const float score = sv[0][t];
        const int   index = si[0][t];
        const int   chan  = index / C_;          // y*W + x
        const int   cls   = index - chan * C_;
        const int   y     = chan >> 9;
        const int   x     = chan & (W_ - 1);

        // last-dim flip: y-component <- channel 1, x-component <- channel 0
        const float offy = off[HW_ + chan];
        const float offx = off[chan];
        const float szy  = sz[HW_ + chan];
        const float szx  = sz[chan];

        const float py = (float)y + offy;
        const float px = (float)x + offx;
        const float hy = 0.5f * szy;
        const float hx = 0.5f * szx;

        const float lo = 0.0f, hi = (float)(W_ - 1);
        out[t * 4 + 0] = fminf(fmaxf(py - hy, lo), hi) * 4.0f;
        out[t * 4 + 1] = fminf(fmaxf(px - hx, lo), hi) * 4.0f;
        out[t * 4 + 2] = fminf(fmaxf(py + hy, lo), hi) * 4.0f;
        out[t * 4 + 3] = fminf(fmaxf(px + hx, lo), hi) * 4.0f;
        out[40 + t]    = (float)cls;   // detection_classes
        out[50 + t]    = score;        // detection_scores
    }
}

// ---------------------------------------------------------------------------
extern "C" void kernel_launch(void* const* d_in, const int* in_sizes, int n_in,
                              void* d_out, int out_size, void* d_ws, size_t ws_size,
                              hipStream_t stream)
{
    const float* off = (const float*)d_in[0];   // [1,2,512,512]
    const float* sz  = (const float*)d_in[1];   // [1,2,512,512]
    const float* kp  = (const float*)d_in[2];   // [1,80,512,512]
    float* outp = (float*)d_out;                // 40 + 10 + 10 = 60 floats

    // ws layout: gbcnt int[2048] @ 0 | gbpair int2[2048*8] @ 16384
    char* w = (char*)d_ws;
    int*  gbcnt  = (int*) (w + 0);
    int2* gbpair = (int2*)(w + 16384);

    k_scan<<<NB2, 256, 0, stream>>>(kp, gbcnt, gbpair);
    k_reduce<<<1, 256, 0, stream>>>(gbcnt, (const int4*)gbpair,
                                    kp, off, sz, outp);
}